// Round 5
// baseline (717.239 us; speedup 1.0000x reference)
//
#include <hip/hip_runtime.h>
#include <math.h>

#define BB 8
#define NVV 2048
#define NPP 4096
#define DD 64
#define NC1 8
#define NC2 4
#define NQ (BB * NVV)   // 16384

// ws layout (floats):
// vm    @0        [16384]
// inv_vf@16384    [16384]
// inv_pf@32768    [32768]
// flow  @65536    [65536]
// pval1 @131072   [NC1*8][16384]
// pidx1 @1179648  [NC1*8][16384]
// pval2 @2228224  [NC2*8][16384]
// pidx2 @2752512  [NC2*8][16384]
// vlist @3276800  [16384] int (batch-major, 2048 slots per batch)
// nvis  @3293184  [8] int          total ~13.2 MB

__device__ __forceinline__ void ins8(float* tv, int* ti, float v, int id) {
  bool c1 = v > tv[1], c2 = v > tv[2], c3 = v > tv[3];
  bool c4 = v > tv[4], c5 = v > tv[5], c6 = v > tv[6], c7 = v > tv[7];
  tv[0] = c1 ? tv[1] : v;               ti[0] = c1 ? ti[1] : id;
  tv[1] = c2 ? tv[2] : (c1 ? v : tv[1]); ti[1] = c2 ? ti[2] : (c1 ? id : ti[1]);
  tv[2] = c3 ? tv[3] : (c2 ? v : tv[2]); ti[2] = c3 ? ti[3] : (c2 ? id : ti[2]);
  tv[3] = c4 ? tv[4] : (c3 ? v : tv[3]); ti[3] = c4 ? ti[4] : (c3 ? id : ti[3]);
  tv[4] = c5 ? tv[5] : (c4 ? v : tv[4]); ti[4] = c5 ? ti[5] : (c4 ? id : ti[4]);
  tv[5] = c6 ? tv[6] : (c5 ? v : tv[5]); ti[5] = c6 ? ti[6] : (c5 ? id : ti[5]);
  tv[6] = c7 ? tv[7] : (c6 ? v : tv[6]); ti[6] = c7 ? ti[7] : (c6 ? id : ti[6]);
  tv[7] = c7 ? v : tv[7];               ti[7] = c7 ? id : ti[7];
}

// ============ kernel 1: vm + visible-list (blocks 0..7), row inv-norms (rest) ============
__global__ __launch_bounds__(256) void k_prep(const float* __restrict__ logits,
                                              const float* __restrict__ vf,
                                              const float* __restrict__ pf,
                                              float* __restrict__ vm,
                                              float* __restrict__ inv_vf,
                                              float* __restrict__ inv_pf,
                                              int* __restrict__ vlist,
                                              int* __restrict__ nvis,
                                              float* __restrict__ out) {
  if (blockIdx.x < BB) {
    int b = blockIdx.x, t = threadIdx.x;
    __shared__ float smn[4], smx[4];
    __shared__ unsigned int lcnt;
    float vals[8];
    float mn = 1e30f, mx = -1e30f;
#pragma unroll
    for (int i = 0; i < 8; i++) {
      float x = logits[b * NVV + t + i * 256];
      float s = 1.0f / (1.0f + expf(-x));
      vals[i] = s;
      mn = fminf(mn, s);
      mx = fmaxf(mx, s);
    }
    for (int o = 32; o; o >>= 1) {
      mn = fminf(mn, __shfl_xor(mn, o, 64));
      mx = fmaxf(mx, __shfl_xor(mx, o, 64));
    }
    int w = t >> 6;
    if ((t & 63) == 0) { smn[w] = mn; smx[w] = mx; }
    if (t == 0) lcnt = 0;
    __syncthreads();
    mn = fminf(fminf(smn[0], smn[1]), fminf(smn[2], smn[3]));
    mx = fmaxf(fmaxf(smx[0], smx[1]), fmaxf(smx[2], smx[3]));
    float range = mx - mn;
#pragma unroll
    for (int i = 0; i < 8; i++) {
      float v = (vals[i] - mn) / range;
      int g = b * NVV + t + i * 256;
      vm[g] = v;
      out[g * 4 + 3] = v;
      if (v >= 0.5f) {
        unsigned p = atomicAdd(&lcnt, 1u);
        vlist[b * NVV + p] = t + i * 256;
      }
    }
    __syncthreads();
    if (t == 0) nvis[b] = (int)lcnt;
  } else {
    int wave = ((blockIdx.x - BB) * 256 + threadIdx.x) >> 6;
    int lane = threadIdx.x & 63;
    const float* src;
    float* dst;
    int row;
    if (wave < NQ) { src = vf; dst = inv_vf; row = wave; }
    else { src = pf; dst = inv_pf; row = wave - NQ; }
    float x = src[row * DD + lane];
    float s = x * x;
    for (int o = 32; o; o >>= 1) s += __shfl_xor(s, o, 64);
    if (lane == 0) dst[row] = 1.0f / fmaxf(sqrtf(s), 1e-12f);
  }
}

// ============ KNN scan: one query/lane, wave-uniform keys, top-8 ============
__device__ __forceinline__ void knn_scan(const float* __restrict__ q,
                                         const float* __restrict__ kbase,
                                         const float* __restrict__ ibase,
                                         const int* __restrict__ list,  // null -> identity
                                         float* __restrict__ pval,
                                         int* __restrict__ pidx,
                                         int qrow, int row0, int p0, int p1) {
  float qv[64];
  const float4* qp = (const float4*)(q + (long)qrow * DD);
#pragma unroll
  for (int c = 0; c < 16; c++) {
    float4 t = qp[c];
    qv[4 * c + 0] = t.x; qv[4 * c + 1] = t.y;
    qv[4 * c + 2] = t.z; qv[4 * c + 3] = t.w;
  }
  // one-shot pin: stop load-sinking into the key loop (R1). Register HOME is
  // handled by amdgpu_waves_per_eu(2,3) on the caller (R2-R4: default
  // occupancy targeting parked this array in AGPRs and shuttled every key).
#pragma unroll
  for (int j = 0; j < 64; j++) asm volatile("" : "+v"(qv[j]));

  float tv[8];
  int ti[8];
#pragma unroll
  for (int k = 0; k < 8; k++) { tv[k] = -3.0e38f; ti[k] = 0; }

  for (int p = p0; p < p1; p++) {
    int pu = __builtin_amdgcn_readfirstlane(list ? list[p] : p);  // uniform key
    const float4* kp = (const float4*)(kbase + (long)pu * DD);
    float a0 = 0.f, a1 = 0.f, a2 = 0.f, a3 = 0.f;
#pragma unroll
    for (int c = 0; c < 16; c++) {
      float4 kv = kp[c];
      a0 = fmaf(kv.x, qv[4 * c + 0], a0);
      a1 = fmaf(kv.y, qv[4 * c + 1], a1);
      a2 = fmaf(kv.z, qv[4 * c + 2], a2);
      a3 = fmaf(kv.w, qv[4 * c + 3], a3);
    }
    float sim = ((a0 + a1) + (a2 + a3)) * ibase[pu];
    if (sim > tv[0]) ins8(tv, ti, sim, pu);
  }
  float* pv = pval + (long)row0 * NQ + qrow;
  int* pi = pidx + (long)row0 * NQ + qrow;
#pragma unroll
  for (int k = 0; k < 8; k++) {
    pv[(long)k * NQ] = tv[k];
    pi[(long)k * NQ] = ti[k];
  }
}

// ============ kernel 2: fused KNN1 + KNN2 ============
__global__ __launch_bounds__(256)
__attribute__((amdgpu_waves_per_eu(2, 3)))
void k_knn2x(const float* __restrict__ vf,
             const float* __restrict__ pf,
             const float* __restrict__ inv_vf,
             const float* __restrict__ inv_pf,
             const int* __restrict__ vlist,
             const int* __restrict__ nvis,
             float* __restrict__ pval1, int* __restrict__ pidx1,
             float* __restrict__ pval2, int* __restrict__ pidx2) {
  int wid = (blockIdx.x * 256 + threadIdx.x) >> 6;  // 0..3071
  int lane = threadIdx.x & 63;
  if (wid < 256 * NC1) {
    int qw = wid >> 3, ck = wid & (NC1 - 1);
    int qrow = qw * 64 + lane;
    int batch = qrow >> 11;
    knn_scan(vf, pf + (long)batch * NPP * DD, inv_pf + (long)batch * NPP,
             nullptr, pval1, pidx1, qrow, ck * 8,
             ck * (NPP / NC1), (ck + 1) * (NPP / NC1));
  } else {
    int w2 = wid - 256 * NC1;
    int qw = w2 >> 2, ck = w2 & (NC2 - 1);
    int qrow = qw * 64 + lane;
    int batch = qrow >> 11;
    int nv = nvis[batch];
    int chunk = (nv + NC2 - 1) >> 2;
    int p0 = ck * chunk;
    int p1 = min(p0 + chunk, nv);
    knn_scan(vf, vf + (long)batch * NVV * DD, inv_vf + (long)batch * NVV,
             vlist + batch * NVV, pval2, pidx2, qrow, ck * 8, p0, p1);
  }
}

__device__ __forceinline__ float dot64(const float4* __restrict__ a,
                                       const float4* __restrict__ b) {
  float a0 = 0.f, a1 = 0.f, a2 = 0.f, a3 = 0.f;
#pragma unroll
  for (int c = 0; c < 16; c++) {
    float4 x = a[c], y = b[c];
    a0 = fmaf(x.x, y.x, a0);
    a1 = fmaf(x.y, y.y, a1);
    a2 = fmaf(x.z, y.z, a2);
    a3 = fmaf(x.w, y.w, a3);
  }
  return (a0 + a1) + (a2 + a3);
}

// slice-merge nrows/4 partials (batched loads), then 2-round butterfly so all
// 4 lanes of a query hold the identical global top-8.
__device__ __forceinline__ void merge4(const float* __restrict__ pval,
                                       const int* __restrict__ pidx,
                                       int g, int sub, int rows_per_sub,
                                       float* tv, int* ti) {
#pragma unroll
  for (int k = 0; k < 8; k++) { tv[k] = -3.0e38f; ti[k] = 0; }
  const float* pv = pval + g;
  const int* pi = pidx + g;
  int j0 = sub * rows_per_sub;
  for (int jb = 0; jb < rows_per_sub; jb += 8) {
    float v[8];
    int id[8];
#pragma unroll
    for (int u = 0; u < 8; u++) {
      v[u] = pv[(long)(j0 + jb + u) * NQ];
      id[u] = pi[(long)(j0 + jb + u) * NQ];
    }
#pragma unroll
    for (int u = 0; u < 8; u++)
      if (v[u] > tv[0]) ins8(tv, ti, v[u], id[u]);
  }
#pragma unroll
  for (int r = 1; r <= 2; r <<= 1) {
    float ov[8];
    int oi[8];
#pragma unroll
    for (int k = 0; k < 8; k++) {
      ov[k] = __shfl_xor(tv[k], r, 64);
      oi[k] = __shfl_xor(ti[k], r, 64);
    }
#pragma unroll
    for (int k = 7; k >= 0; k--)
      if (ov[k] > tv[0]) ins8(tv, ti, ov[k], oi[k]);
  }
}

__device__ __forceinline__ int pick(const int* ti, int s) {
  int a = ti[0], b = ti[2], c = ti[4], d = ti[6];
  int lo = (s & 2) ? ((s & 1) ? d : c) : ((s & 1) ? b : a);
  return lo;
}
__device__ __forceinline__ int pick1(const int* ti, int s) {
  int a = ti[1], b = ti[3], c = ti[5], d = ti[7];
  return (s & 2) ? ((s & 1) ? d : c) : ((s & 1) ? b : a);
}

// ============ kernel 3: merge KNN1 + flow_init (4 lanes / query) ============
__global__ __launch_bounds__(256) void k_merge_flow(const float* __restrict__ pval,
                                                    const int* __restrict__ pidx,
                                                    const float* __restrict__ vf,
                                                    const float* __restrict__ pf,
                                                    const float* __restrict__ pts,
                                                    const float* __restrict__ vtx,
                                                    float* __restrict__ flow_ws,
                                                    float* __restrict__ out) {
  int T = blockIdx.x * 256 + threadIdx.x;
  int g = T >> 2, sub = T & 3;
  int batch = g >> 11;
  float tv[8];
  int ti[8];
  merge4(pval, pidx, g, sub, (NC1 * 8) / 4, tv, ti);

  const float4* qp = (const float4*)(vf + (long)g * DD);
  int i0 = pick(ti, sub), i1 = pick1(ti, sub);
  float ax = 0.f, ay = 0.f, az = 0.f, den = 0.f;
  float vx = vtx[g * 3 + 0], vy = vtx[g * 3 + 1], vz = vtx[g * 3 + 2];
#pragma unroll
  for (int kk = 0; kk < 2; kk++) {
    int idx = kk ? i1 : i0;
    int prow = batch * NPP + idx;
    float w = dot64(qp, (const float4*)(pf + (long)prow * DD));
    ax = fmaf(pts[prow * 3 + 0] - vx, w, ax);
    ay = fmaf(pts[prow * 3 + 1] - vy, w, ay);
    az = fmaf(pts[prow * 3 + 2] - vz, w, az);
    den += w;
  }
#pragma unroll
  for (int r = 1; r <= 2; r <<= 1) {
    ax += __shfl_xor(ax, r, 64);
    ay += __shfl_xor(ay, r, 64);
    az += __shfl_xor(az, r, 64);
    den += __shfl_xor(den, r, 64);
  }
  if (sub == 0) {
    float fx = ax / den, fy = ay / den, fz = az / den;
    flow_ws[g * 4 + 0] = fx;
    flow_ws[g * 4 + 1] = fy;
    flow_ws[g * 4 + 2] = fz;
    out[g * 4 + 0] = fx;
    out[g * 4 + 1] = fy;
    out[g * 4 + 2] = fz;
  }
}

// ============ kernel 4: merge KNN2 + interpolate invisible ============
__global__ __launch_bounds__(256) void k_merge_final(const float* __restrict__ pval,
                                                     const int* __restrict__ pidx,
                                                     const float* __restrict__ vf,
                                                     const float* __restrict__ vm,
                                                     const float* __restrict__ flow_ws,
                                                     float* __restrict__ out) {
  int T = blockIdx.x * 256 + threadIdx.x;
  int g = T >> 2, sub = T & 3;
  if (vm[g] >= 0.5f) return;
  int batch = g >> 11;
  float tv[8];
  int ti[8];
  merge4(pval, pidx, g, sub, (NC2 * 8) / 4, tv, ti);

  const float4* qp = (const float4*)(vf + (long)g * DD);
  int i0 = pick(ti, sub), i1 = pick1(ti, sub);
  float ax = 0.f, ay = 0.f, az = 0.f, den = 0.f;
#pragma unroll
  for (int kk = 0; kk < 2; kk++) {
    int idx = kk ? i1 : i0;
    int krow = batch * NVV + idx;
    float w = dot64(qp, (const float4*)(vf + (long)krow * DD));
    ax = fmaf(flow_ws[krow * 4 + 0], w, ax);
    ay = fmaf(flow_ws[krow * 4 + 1], w, ay);
    az = fmaf(flow_ws[krow * 4 + 2], w, az);
    den += w;
  }
#pragma unroll
  for (int r = 1; r <= 2; r <<= 1) {
    ax += __shfl_xor(ax, r, 64);
    ay += __shfl_xor(ay, r, 64);
    az += __shfl_xor(az, r, 64);
    den += __shfl_xor(den, r, 64);
  }
  if (sub == 0) {
    out[g * 4 + 0] = ax / den;
    out[g * 4 + 1] = ay / den;
    out[g * 4 + 2] = az / den;
  }
}

extern "C" void kernel_launch(void* const* d_in, const int* in_sizes, int n_in,
                              void* d_out, int out_size, void* d_ws, size_t ws_size,
                              hipStream_t stream) {
  const float* vtx = (const float*)d_in[0];
  const float* pts = (const float*)d_in[1];
  const float* vf = (const float*)d_in[2];
  const float* pf = (const float*)d_in[3];
  const float* lg = (const float*)d_in[4];
  float* out = (float*)d_out;
  float* ws = (float*)d_ws;

  float* vm = ws;
  float* inv_vf = ws + 16384;
  float* inv_pf = ws + 32768;
  float* flow = ws + 65536;
  float* pval1 = ws + 131072;
  int* pidx1 = (int*)(pval1 + (size_t)NC1 * 8 * NQ);
  float* pval2 = (float*)(pidx1 + (size_t)NC1 * 8 * NQ);
  int* pidx2 = (int*)(pval2 + (size_t)NC2 * 8 * NQ);
  int* vlist = (int*)(pidx2 + (size_t)NC2 * 8 * NQ);
  int* nvis = vlist + NQ;

  k_prep<<<BB + (NQ + BB * NPP) / 4, 256, 0, stream>>>(lg, vf, pf, vm, inv_vf, inv_pf,
                                                       vlist, nvis, out);
  k_knn2x<<<(256 * NC1 + 256 * NC2) / 4, 256, 0, stream>>>(vf, pf, inv_vf, inv_pf,
                                                           vlist, nvis,
                                                           pval1, pidx1, pval2, pidx2);
  k_merge_flow<<<NQ * 4 / 256, 256, 0, stream>>>(pval1, pidx1, vf, pf, pts, vtx, flow, out);
  k_merge_final<<<NQ * 4 / 256, 256, 0, stream>>>(pval2, pidx2, vf, vm, flow, out);
}

// Round 7
// 299.846 us; speedup vs baseline: 2.3920x; 2.3920x over previous
//
#include <hip/hip_runtime.h>
#include <math.h>

#define BB 8
#define NVV 2048
#define NPP 4096
#define DD 64
#define NQ (BB * NVV)     // 16384 vertex rows
#define NROWP (BB * NPP)  // 32768 point rows
#define QT (NQ / 16)      // 1024 query tiles (A/B frags of vf)
#define PT (NROWP / 16)   // 2048 key tiles  (B frags of pf)
#define NC1 4             // key chunks KNN1 (64 tiles each)
#define NC2 2             // key chunks KNN2 (64 tiles each)

typedef __attribute__((ext_vector_type(8))) short short8;
typedef __attribute__((ext_vector_type(8))) unsigned short ushort8;
typedef __attribute__((ext_vector_type(4))) float f32x4;

// ws layout (float offsets):
// vm 0 | inv_vf 16384 | inv_pf 32768 | flow 65536
// pval1 @131072  [32][NQ]   pidx1 @655360 [32][NQ]
// pval2 @1179648 [16][NQ]   pidx2 @1441792 [16][NQ]
// qhi @1703936 (1Mi ushort) qlo @2228224 | khi @2752512 (2Mi ushort) klo @3801088
// end 4849664 floats = 19.4 MB

__device__ __forceinline__ unsigned short bf16rn(float x) {
  unsigned u = __float_as_uint(x);
  return (unsigned short)((u + 0x7FFFu + ((u >> 16) & 1u)) >> 16);
}
__device__ __forceinline__ float bf2f(unsigned short h) {
  return __uint_as_float(((unsigned)h) << 16);
}

__device__ __forceinline__ void ins8(float* tv, int* ti, float v, int id) {
  bool c1 = v > tv[1], c2 = v > tv[2], c3 = v > tv[3];
  bool c4 = v > tv[4], c5 = v > tv[5], c6 = v > tv[6], c7 = v > tv[7];
  tv[0] = c1 ? tv[1] : v;                ti[0] = c1 ? ti[1] : id;
  tv[1] = c2 ? tv[2] : (c1 ? v : tv[1]); ti[1] = c2 ? ti[2] : (c1 ? id : ti[1]);
  tv[2] = c3 ? tv[3] : (c2 ? v : tv[2]); ti[2] = c3 ? ti[3] : (c2 ? id : ti[2]);
  tv[3] = c4 ? tv[4] : (c3 ? v : tv[3]); ti[3] = c4 ? ti[4] : (c3 ? id : ti[3]);
  tv[4] = c5 ? tv[5] : (c4 ? v : tv[4]); ti[4] = c5 ? ti[5] : (c4 ? id : ti[4]);
  tv[5] = c6 ? tv[6] : (c5 ? v : tv[5]); ti[5] = c6 ? ti[6] : (c5 ? id : ti[5]);
  tv[6] = c7 ? tv[7] : (c6 ? v : tv[6]); ti[6] = c7 ? ti[7] : (c6 ? id : ti[6]);
  tv[7] = c7 ? v : tv[7];                ti[7] = c7 ? id : ti[7];
}

// ===== kernel 1: vm (blocks 0..7) + inv-norms (next 3072) + bf16 frag staging =====
// Fragment gather (A and B identical): frag[tile][kk][lane][j] =
//   M[tile*16 + (lane&15)][kk*32 + (lane>>4)*8 + j], hi/lo bf16 split.
__global__ __launch_bounds__(256) void k_prep(const float* __restrict__ logits,
                                              const float* __restrict__ vf,
                                              const float* __restrict__ pf,
                                              float* __restrict__ vm,
                                              float* __restrict__ inv_vf,
                                              float* __restrict__ inv_pf,
                                              unsigned short* __restrict__ qhi,
                                              unsigned short* __restrict__ qlo,
                                              unsigned short* __restrict__ khi,
                                              unsigned short* __restrict__ klo,
                                              float* __restrict__ out) {
  int bid = blockIdx.x, t = threadIdx.x;
  if (bid < BB) {
    int b = bid;
    __shared__ float smn[4], smx[4];
    float vals[8];
    float mn = 1e30f, mx = -1e30f;
#pragma unroll
    for (int i = 0; i < 8; i++) {
      float x = logits[b * NVV + t + i * 256];
      float s = 1.0f / (1.0f + expf(-x));
      vals[i] = s;
      mn = fminf(mn, s);
      mx = fmaxf(mx, s);
    }
    for (int o = 32; o; o >>= 1) {
      mn = fminf(mn, __shfl_xor(mn, o, 64));
      mx = fmaxf(mx, __shfl_xor(mx, o, 64));
    }
    int w = t >> 6;
    if ((t & 63) == 0) { smn[w] = mn; smx[w] = mx; }
    __syncthreads();
    mn = fminf(fminf(smn[0], smn[1]), fminf(smn[2], smn[3]));
    mx = fmaxf(fmaxf(smx[0], smx[1]), fmaxf(smx[2], smx[3]));
    float range = mx - mn;
#pragma unroll
    for (int i = 0; i < 8; i++) {
      float v = (vals[i] - mn) / range;
      int g = b * NVV + t + i * 256;
      vm[g] = v;
      out[g * 4 + 3] = v;
    }
  } else if (bid < BB + 3072) {
    // inverse norms: 16 lanes per row
    int T = (bid - BB) * 256 + t;
    int row = T >> 4, c = T & 15;
    const float* src;
    float* dst;
    int r;
    if (row < NQ) { src = vf; dst = inv_vf; r = row; }
    else { src = pf; dst = inv_pf; r = row - NQ; }
    float4 v = *(const float4*)(src + (size_t)r * DD + c * 4);
    float s = v.x * v.x + v.y * v.y + v.z * v.z + v.w * v.w;
#pragma unroll
    for (int m = 1; m <= 8; m <<= 1) s += __shfl_xor(s, m, 64);
    if (c == 0) dst[r] = 1.0f / fmaxf(sqrtf(s), 1e-12f);
  } else {
    // staging: one thread = one (tile,kk,lane) slot of 8 elems
    int T = (bid - BB - 3072) * 256 + t;  // 0..393215
    const float* src;
    unsigned short *dh, *dl;
    int s;
    if (T < QT * 128) { s = T; src = vf; dh = qhi; dl = qlo; }
    else { s = T - QT * 128; src = pf; dh = khi; dl = klo; }
    int lane = s & 63, kk = (s >> 6) & 1, tile = s >> 7;
    size_t off = (size_t)(tile * 16 + (lane & 15)) * DD + kk * 32 + ((lane >> 4) & 3) * 8;
    float4 a = *(const float4*)(src + off);
    float4 b = *(const float4*)(src + off + 4);
    float xs[8] = {a.x, a.y, a.z, a.w, b.x, b.y, b.z, b.w};
    ushort8 h, l;
#pragma unroll
    for (int j = 0; j < 8; j++) {
      unsigned short hj = bf16rn(xs[j]);
      h[j] = hj;
      l[j] = bf16rn(xs[j] - bf2f(hj));
    }
    *(ushort8*)(dh + (size_t)s * 8) = h;
    *(ushort8*)(dl + (size_t)s * 8) = l;
  }
}

// ===== kernel 2: MFMA KNN candidate generation (fused KNN1 + KNN2) =====
// Wave = 16 queries (one A tile) x 64 key tiles. Per tile: 6 MFMAs (2 K-halves
// x {hi*hi, hi*lo, lo*hi}), per-lane insert into 4 top-8 lists (C rows), then
// one col-butterfly per scan, col==0 lanes store chunk partials.
// Approx sims (~6e-5 abs) are ONLY used to pick per-chunk top-8 candidate
// supersets; exact fp32 re-ranking happens in the merge kernels (R6 lesson:
// selection directly on bf16x3 sims flips ~#8/#9 neighbors and fails).
__global__ __launch_bounds__(256) __attribute__((amdgpu_waves_per_eu(3)))
void k_knn(const unsigned short* __restrict__ qhi, const unsigned short* __restrict__ qlo,
           const unsigned short* __restrict__ khi, const unsigned short* __restrict__ klo,
           const float* __restrict__ inv_vf, const float* __restrict__ inv_pf,
           const float* __restrict__ vm,
           float* __restrict__ pval1, int* __restrict__ pidx1,
           float* __restrict__ pval2, int* __restrict__ pidx2) {
  int wid = (blockIdx.x * 256 + threadIdx.x) >> 6;
  int lane = threadIdx.x & 63, col = lane & 15, quad = lane >> 4;

  const unsigned short *BH, *BL;
  const float *inv, *mask;
  float* PV;
  int* PI;
  int qt_g, bt0, row0, ckb;
  if (wid < QT * NC1) {  // KNN1: keys = pf
    int ck = wid & (NC1 - 1);
    qt_g = wid >> 2;
    int batch = qt_g >> 7;
    BH = khi; BL = klo;
    inv = inv_pf + batch * NPP;
    mask = nullptr;
    bt0 = batch * 256 + ck * 64;
    PV = pval1; PI = pidx1;
    row0 = ck * 8; ckb = ck * 64;
  } else {               // KNN2: keys = vf, visible only
    int w = wid - QT * NC1;
    int ck = w & (NC2 - 1);
    qt_g = w >> 1;
    int batch = qt_g >> 7;
    BH = qhi; BL = qlo;
    inv = inv_vf + batch * NVV;
    mask = vm + batch * NVV;
    bt0 = batch * 128 + ck * 64;
    PV = pval2; PI = pidx2;
    row0 = ck * 8; ckb = ck * 64;
  }

  size_t ab = (size_t)qt_g * 1024 + lane * 8;
  short8 ah0 = *(const short8*)(qhi + ab);
  short8 ah1 = *(const short8*)(qhi + ab + 512);
  short8 al0 = *(const short8*)(qlo + ab);
  short8 al1 = *(const short8*)(qlo + ab + 512);

  float tv[4][8];
  int ti[4][8];
#pragma unroll
  for (int r = 0; r < 4; r++)
#pragma unroll
    for (int k = 0; k < 8; k++) { tv[r][k] = -3.0e38f; ti[r][k] = 0; }

  for (int kt = 0; kt < 64; kt++) {
    size_t bo = (size_t)(bt0 + kt) * 1024 + lane * 8;
    short8 bh0 = *(const short8*)(BH + bo);
    short8 bh1 = *(const short8*)(BH + bo + 512);
    short8 bl0 = *(const short8*)(BL + bo);
    short8 bl1 = *(const short8*)(BL + bo + 512);
    int key = (ckb + kt) * 16 + col;
    float iv = inv[key];
    bool ok = mask ? (mask[key] >= 0.5f) : true;
    f32x4 c0 = {0.f, 0.f, 0.f, 0.f}, c1 = {0.f, 0.f, 0.f, 0.f};
    c0 = __builtin_amdgcn_mfma_f32_16x16x32_bf16(ah0, bh0, c0, 0, 0, 0);
    c1 = __builtin_amdgcn_mfma_f32_16x16x32_bf16(ah1, bh1, c1, 0, 0, 0);
    c0 = __builtin_amdgcn_mfma_f32_16x16x32_bf16(ah0, bl0, c0, 0, 0, 0);
    c1 = __builtin_amdgcn_mfma_f32_16x16x32_bf16(ah1, bl1, c1, 0, 0, 0);
    c0 = __builtin_amdgcn_mfma_f32_16x16x32_bf16(al0, bh0, c0, 0, 0, 0);
    c1 = __builtin_amdgcn_mfma_f32_16x16x32_bf16(al1, bh1, c1, 0, 0, 0);
#pragma unroll
    for (int r = 0; r < 4; r++) {
      float s = (c0[r] + c1[r]) * iv;
      s = ok ? s : -3.0e38f;
      if (s > tv[r][0]) ins8(tv[r], ti[r], s, key);
    }
  }

  // butterfly across the 16 cols (lane bits 0..3)
#pragma unroll
  for (int m = 1; m <= 8; m <<= 1) {
#pragma unroll
    for (int r = 0; r < 4; r++) {
      float ov[8];
      int oi[8];
#pragma unroll
      for (int k = 0; k < 8; k++) {
        ov[k] = __shfl_xor(tv[r][k], m, 64);
        oi[k] = __shfl_xor(ti[r][k], m, 64);
      }
#pragma unroll
      for (int k = 7; k >= 0; k--)
        if (ov[k] > tv[r][0]) ins8(tv[r], ti[r], ov[k], oi[k]);
    }
  }

  if (col == 0) {
#pragma unroll
    for (int r = 0; r < 4; r++) {
      int q = qt_g * 16 + quad * 4 + r;
#pragma unroll
      for (int k = 0; k < 8; k++) {
        PV[(size_t)(row0 + k) * NQ + q] = tv[r][k];
        PI[(size_t)(row0 + k) * NQ + q] = ti[r][k];
      }
    }
  }
}

__device__ __forceinline__ float dot64(const float4* __restrict__ a,
                                       const float4* __restrict__ b) {
  float a0 = 0.f, a1 = 0.f, a2 = 0.f, a3 = 0.f;
#pragma unroll
  for (int c = 0; c < 16; c++) {
    float4 x = a[c], y = b[c];
    a0 = fmaf(x.x, y.x, a0);
    a1 = fmaf(x.y, y.y, a1);
    a2 = fmaf(x.z, y.z, a2);
    a3 = fmaf(x.w, y.w, a3);
  }
  return (a0 + a1) + (a2 + a3);
}

// ===== kernel 3: exact re-rank of 32 KNN1 candidates + flow_init (16 lanes/q) =====
__global__ __launch_bounds__(256) void k_merge_flow(const float* __restrict__ pval,
                                                    const int* __restrict__ pidx,
                                                    const float* __restrict__ vf,
                                                    const float* __restrict__ pf,
                                                    const float* __restrict__ pts,
                                                    const float* __restrict__ vtx,
                                                    const float* __restrict__ inv_pf,
                                                    float* __restrict__ flow_ws,
                                                    float* __restrict__ out) {
  int T = blockIdx.x * 256 + threadIdx.x;
  int q = T >> 4, c = T & 15, batch = q >> 11;
  const float4* qp = (const float4*)(vf + (size_t)q * DD);
  float tv[8];
  int ti[8];
#pragma unroll
  for (int k = 0; k < 8; k++) { tv[k] = -3.0e38f; ti[k] = 0; }
#pragma unroll
  for (int u = 0; u < 2; u++) {  // 32 candidate rows / 16 lanes
    int row = c * 2 + u;
    int id = pidx[(size_t)row * NQ + q];
    float pv = pval[(size_t)row * NQ + q];
    if (pv > -1e37f) {
      int prow = batch * NPP + id;
      float s = dot64(qp, (const float4*)(pf + (size_t)prow * DD)) * inv_pf[prow];
      if (s > tv[0]) ins8(tv, ti, s, id);
    }
  }
#pragma unroll
  for (int m = 1; m <= 8; m <<= 1) {
    float ov[8];
    int oi[8];
#pragma unroll
    for (int k = 0; k < 8; k++) {
      ov[k] = __shfl_xor(tv[k], m, 64);
      oi[k] = __shfl_xor(ti[k], m, 64);
    }
#pragma unroll
    for (int k = 7; k >= 0; k--)
      if (ov[k] > tv[0]) ins8(tv, ti, ov[k], oi[k]);
  }
  int id = ti[0];
#pragma unroll
  for (int k = 1; k < 8; k++) id = (c == k) ? ti[k] : id;

  float ax = 0.f, ay = 0.f, az = 0.f, den = 0.f;
  if (c < 8) {
    int prow = batch * NPP + id;
    float w = dot64(qp, (const float4*)(pf + (size_t)prow * DD));
    ax = (pts[prow * 3 + 0] - vtx[q * 3 + 0]) * w;
    ay = (pts[prow * 3 + 1] - vtx[q * 3 + 1]) * w;
    az = (pts[prow * 3 + 2] - vtx[q * 3 + 2]) * w;
    den = w;
  }
#pragma unroll
  for (int m = 1; m <= 8; m <<= 1) {
    ax += __shfl_xor(ax, m, 64);
    ay += __shfl_xor(ay, m, 64);
    az += __shfl_xor(az, m, 64);
    den += __shfl_xor(den, m, 64);
  }
  if (c == 0) {
    float fx = ax / den, fy = ay / den, fz = az / den;
    flow_ws[q * 4 + 0] = fx;
    flow_ws[q * 4 + 1] = fy;
    flow_ws[q * 4 + 2] = fz;
    out[q * 4 + 0] = fx;
    out[q * 4 + 1] = fy;
    out[q * 4 + 2] = fz;
  }
}

// ===== kernel 4: exact re-rank of 16 KNN2 candidates + interpolate invisible =====
__global__ __launch_bounds__(256) void k_merge_final(const float* __restrict__ pval,
                                                     const int* __restrict__ pidx,
                                                     const float* __restrict__ vf,
                                                     const float* __restrict__ vm,
                                                     const float* __restrict__ inv_vf,
                                                     const float* __restrict__ flow_ws,
                                                     float* __restrict__ out) {
  int T = blockIdx.x * 256 + threadIdx.x;
  int q = T >> 4, c = T & 15, batch = q >> 11;
  if (vm[q] >= 0.5f) return;
  const float4* qp = (const float4*)(vf + (size_t)q * DD);
  float tv[8];
  int ti[8];
#pragma unroll
  for (int k = 0; k < 8; k++) { tv[k] = -3.0e38f; ti[k] = 0; }
  {  // 16 candidate rows / 16 lanes
    int row = c;
    int id = pidx[(size_t)row * NQ + q];
    float pv = pval[(size_t)row * NQ + q];
    if (pv > -1e37f) {
      int krow = batch * NVV + id;
      float s = dot64(qp, (const float4*)(vf + (size_t)krow * DD)) * inv_vf[krow];
      if (s > tv[0]) ins8(tv, ti, s, id);
    }
  }
#pragma unroll
  for (int m = 1; m <= 8; m <<= 1) {
    float ov[8];
    int oi[8];
#pragma unroll
    for (int k = 0; k < 8; k++) {
      ov[k] = __shfl_xor(tv[k], m, 64);
      oi[k] = __shfl_xor(ti[k], m, 64);
    }
#pragma unroll
    for (int k = 7; k >= 0; k--)
      if (ov[k] > tv[0]) ins8(tv, ti, ov[k], oi[k]);
  }
  int id = ti[0];
#pragma unroll
  for (int k = 1; k < 8; k++) id = (c == k) ? ti[k] : id;

  float ax = 0.f, ay = 0.f, az = 0.f, den = 0.f;
  if (c < 8) {
    int krow = batch * NVV + id;
    float w = dot64(qp, (const float4*)(vf + (size_t)krow * DD));
    ax = flow_ws[krow * 4 + 0] * w;
    ay = flow_ws[krow * 4 + 1] * w;
    az = flow_ws[krow * 4 + 2] * w;
    den = w;
  }
#pragma unroll
  for (int m = 1; m <= 8; m <<= 1) {
    ax += __shfl_xor(ax, m, 64);
    ay += __shfl_xor(ay, m, 64);
    az += __shfl_xor(az, m, 64);
    den += __shfl_xor(den, m, 64);
  }
  if (c == 0) {
    out[q * 4 + 0] = ax / den;
    out[q * 4 + 1] = ay / den;
    out[q * 4 + 2] = az / den;
  }
}

extern "C" void kernel_launch(void* const* d_in, const int* in_sizes, int n_in,
                              void* d_out, int out_size, void* d_ws, size_t ws_size,
                              hipStream_t stream) {
  const float* vtx = (const float*)d_in[0];
  const float* pts = (const float*)d_in[1];
  const float* vf = (const float*)d_in[2];
  const float* pf = (const float*)d_in[3];
  const float* lg = (const float*)d_in[4];
  float* out = (float*)d_out;
  float* ws = (float*)d_ws;

  float* vm = ws;
  float* inv_vf = ws + 16384;
  float* inv_pf = ws + 32768;
  float* flow = ws + 65536;
  float* pval1 = ws + 131072;
  int* pidx1 = (int*)(ws + 655360);
  float* pval2 = ws + 1179648;
  int* pidx2 = (int*)(ws + 1441792);
  unsigned short* qhi = (unsigned short*)(ws + 1703936);
  unsigned short* qlo = (unsigned short*)(ws + 2228224);
  unsigned short* khi = (unsigned short*)(ws + 2752512);
  unsigned short* klo = (unsigned short*)(ws + 3801088);

  k_prep<<<BB + 3072 + 1536, 256, 0, stream>>>(lg, vf, pf, vm, inv_vf, inv_pf,
                                               qhi, qlo, khi, klo, out);
  k_knn<<<(QT * NC1 + QT * NC2) / 4, 256, 0, stream>>>(qhi, qlo, khi, klo,
                                                       inv_vf, inv_pf, vm,
                                                       pval1, pidx1, pval2, pidx2);
  k_merge_flow<<<NQ * 16 / 256, 256, 0, stream>>>(pval1, pidx1, vf, pf, pts, vtx,
                                                  inv_pf, flow, out);
  k_merge_final<<<NQ * 16 / 256, 256, 0, stream>>>(pval2, pidx2, vf, vm, inv_vf, flow, out);
}

// Round 8
// 260.286 us; speedup vs baseline: 2.7556x; 1.1520x over previous
//
#include <hip/hip_runtime.h>
#include <math.h>

#define BB 8
#define NVV 2048
#define NPP 4096
#define DD 64
#define NQ (BB * NVV)     // 16384 vertex rows
#define QT (NQ / 16)      // 1024 query tiles
#define NC1 4             // key chunks KNN1 (64 tiles each)
#define NC2 2             // key chunks KNN2 (64 tiles each)

typedef __attribute__((ext_vector_type(8))) short short8;
typedef __attribute__((ext_vector_type(8))) unsigned short ushort8;
typedef __attribute__((ext_vector_type(4))) float f32x4;

// ws layout (float offsets):
// vm 0 | inv_vf 16384 | inv_pf 32768 | flow 65536
// pc1 @131072  [32][NQ] uint (packed sim|key candidates)
// pc2 @655360  [16][NQ] uint
// qhi @917504 (1Mi ushort) qlo @1441792 | khi @1966080 (2Mi ushort) klo @3014656
// end 4062208 floats = 16.2 MB

__device__ __forceinline__ unsigned short bf16rn(float x) {
  unsigned u = __float_as_uint(x);
  return (unsigned short)((u + 0x7FFFu + ((u >> 16) & 1u)) >> 16);
}
__device__ __forceinline__ float bf2f(unsigned short h) {
  return __uint_as_float(((unsigned)h) << 16);
}
// monotone float -> uint (total order preserved)
__device__ __forceinline__ unsigned fsort(float f) {
  unsigned u = __float_as_uint(f);
  return u ^ (unsigned)(((int)u >> 31) | 0x80000000);
}

// sorted-ascending top-8 insert, single packed array: 7 cmp + 14 cndmask
__device__ __forceinline__ void ins8u(unsigned* tv, unsigned v) {
  bool c1 = v > tv[1], c2 = v > tv[2], c3 = v > tv[3];
  bool c4 = v > tv[4], c5 = v > tv[5], c6 = v > tv[6], c7 = v > tv[7];
  tv[0] = c1 ? tv[1] : v;
  tv[1] = c2 ? tv[2] : (c1 ? v : tv[1]);
  tv[2] = c3 ? tv[3] : (c2 ? v : tv[2]);
  tv[3] = c4 ? tv[4] : (c3 ? v : tv[3]);
  tv[4] = c5 ? tv[5] : (c4 ? v : tv[4]);
  tv[5] = c6 ? tv[6] : (c5 ? v : tv[5]);
  tv[6] = c7 ? tv[7] : (c6 ? v : tv[6]);
  tv[7] = c7 ? v : tv[7];
}

__device__ __forceinline__ void ins8(float* tv, int* ti, float v, int id) {
  bool c1 = v > tv[1], c2 = v > tv[2], c3 = v > tv[3];
  bool c4 = v > tv[4], c5 = v > tv[5], c6 = v > tv[6], c7 = v > tv[7];
  tv[0] = c1 ? tv[1] : v;                ti[0] = c1 ? ti[1] : id;
  tv[1] = c2 ? tv[2] : (c1 ? v : tv[1]); ti[1] = c2 ? ti[2] : (c1 ? id : ti[1]);
  tv[2] = c3 ? tv[3] : (c2 ? v : tv[2]); ti[2] = c3 ? ti[3] : (c2 ? id : ti[2]);
  tv[3] = c4 ? tv[4] : (c3 ? v : tv[3]); ti[3] = c4 ? ti[4] : (c3 ? id : ti[3]);
  tv[4] = c5 ? tv[5] : (c4 ? v : tv[4]); ti[4] = c5 ? ti[5] : (c4 ? id : ti[4]);
  tv[5] = c6 ? tv[6] : (c5 ? v : tv[5]); ti[5] = c6 ? ti[6] : (c5 ? id : ti[5]);
  tv[6] = c7 ? tv[7] : (c6 ? v : tv[6]); ti[6] = c7 ? ti[7] : (c6 ? id : ti[6]);
  tv[7] = c7 ? v : tv[7];                ti[7] = c7 ? id : ti[7];
}

// ===== kernel 1: vm (blocks 0..7) + inv-norms (next 3072) + bf16 frag staging =====
__global__ __launch_bounds__(256) void k_prep(const float* __restrict__ logits,
                                              const float* __restrict__ vf,
                                              const float* __restrict__ pf,
                                              float* __restrict__ vm,
                                              float* __restrict__ inv_vf,
                                              float* __restrict__ inv_pf,
                                              unsigned short* __restrict__ qhi,
                                              unsigned short* __restrict__ qlo,
                                              unsigned short* __restrict__ khi,
                                              unsigned short* __restrict__ klo,
                                              float* __restrict__ out) {
  int bid = blockIdx.x, t = threadIdx.x;
  if (bid < BB) {
    int b = bid;
    __shared__ float smn[4], smx[4];
    float vals[8];
    float mn = 1e30f, mx = -1e30f;
#pragma unroll
    for (int i = 0; i < 8; i++) {
      float x = logits[b * NVV + t + i * 256];
      float s = 1.0f / (1.0f + expf(-x));
      vals[i] = s;
      mn = fminf(mn, s);
      mx = fmaxf(mx, s);
    }
    for (int o = 32; o; o >>= 1) {
      mn = fminf(mn, __shfl_xor(mn, o, 64));
      mx = fmaxf(mx, __shfl_xor(mx, o, 64));
    }
    int w = t >> 6;
    if ((t & 63) == 0) { smn[w] = mn; smx[w] = mx; }
    __syncthreads();
    mn = fminf(fminf(smn[0], smn[1]), fminf(smn[2], smn[3]));
    mx = fmaxf(fmaxf(smx[0], smx[1]), fmaxf(smx[2], smx[3]));
    float range = mx - mn;
#pragma unroll
    for (int i = 0; i < 8; i++) {
      float v = (vals[i] - mn) / range;
      int g = b * NVV + t + i * 256;
      vm[g] = v;
      out[g * 4 + 3] = v;
    }
  } else if (bid < BB + 3072) {
    int T = (bid - BB) * 256 + t;
    int row = T >> 4, c = T & 15;
    const float* src;
    float* dst;
    int r;
    if (row < NQ) { src = vf; dst = inv_vf; r = row; }
    else { src = pf; dst = inv_pf; r = row - NQ; }
    float4 v = *(const float4*)(src + (size_t)r * DD + c * 4);
    float s = v.x * v.x + v.y * v.y + v.z * v.z + v.w * v.w;
#pragma unroll
    for (int m = 1; m <= 8; m <<= 1) s += __shfl_xor(s, m, 64);
    if (c == 0) dst[r] = 1.0f / fmaxf(sqrtf(s), 1e-12f);
  } else {
    // staging: one thread = one (tile,kk,lane) slot of 8 elems; hi/lo bf16 split
    int T = (bid - BB - 3072) * 256 + t;  // 0..393215
    const float* src;
    unsigned short *dh, *dl;
    int s;
    if (T < QT * 128) { s = T; src = vf; dh = qhi; dl = qlo; }
    else { s = T - QT * 128; src = pf; dh = khi; dl = klo; }
    int lane = s & 63, kk = (s >> 6) & 1, tile = s >> 7;
    size_t off = (size_t)(tile * 16 + (lane & 15)) * DD + kk * 32 + ((lane >> 4) & 3) * 8;
    float4 a = *(const float4*)(src + off);
    float4 b = *(const float4*)(src + off + 4);
    float xs[8] = {a.x, a.y, a.z, a.w, b.x, b.y, b.z, b.w};
    ushort8 h, l;
#pragma unroll
    for (int j = 0; j < 8; j++) {
      unsigned short hj = bf16rn(xs[j]);
      h[j] = hj;
      l[j] = bf16rn(xs[j] - bf2f(hj));
    }
    *(ushort8*)(dh + (size_t)s * 8) = h;
    *(ushort8*)(dl + (size_t)s * 8) = l;
  }
}

// ===== kernel 2: MFMA KNN candidate generation (fused KNN1 + KNN2) =====
// Wave = 16 queries (one A tile) x 64 key tiles, 6 MFMAs/tile (hi/lo split).
// Top-8 lists are PACKED uints: [20-bit monotone sim | 12-bit key] -> one
// sorted array per C-row, half the cndmask of the float+int version (R7:
// VALUBusy 84% was the ins8 chains). Approx+quantized sims only pick
// per-chunk candidate supersets; merges re-rank in exact fp32 (R6 lesson).
__global__ __launch_bounds__(256)
void k_knn(const unsigned short* __restrict__ qhi, const unsigned short* __restrict__ qlo,
           const unsigned short* __restrict__ khi, const unsigned short* __restrict__ klo,
           const float* __restrict__ inv_vf, const float* __restrict__ inv_pf,
           const float* __restrict__ vm,
           unsigned* __restrict__ pc1, unsigned* __restrict__ pc2) {
  int wid = (blockIdx.x * 256 + threadIdx.x) >> 6;
  int lane = threadIdx.x & 63, col = lane & 15, quad = lane >> 4;

  const unsigned short *BH, *BL;
  const float *inv, *mask;
  unsigned* PC;
  int qt_g, bt0, row0, ckb;
  if (wid < QT * NC1) {  // KNN1: keys = pf
    int ck = wid & (NC1 - 1);
    qt_g = wid >> 2;
    int batch = qt_g >> 7;
    BH = khi; BL = klo;
    inv = inv_pf + batch * NPP;
    mask = nullptr;
    bt0 = batch * 256 + ck * 64;
    PC = pc1;
    row0 = ck * 8; ckb = ck * 64;
  } else {               // KNN2: keys = vf, visible only
    int w = wid - QT * NC1;
    int ck = w & (NC2 - 1);
    qt_g = w >> 1;
    int batch = qt_g >> 7;
    BH = qhi; BL = qlo;
    inv = inv_vf + batch * NVV;
    mask = vm + batch * NVV;
    bt0 = batch * 128 + ck * 64;
    PC = pc2;
    row0 = ck * 8; ckb = ck * 64;
  }

  size_t ab = (size_t)qt_g * 1024 + lane * 8;
  short8 ah0 = *(const short8*)(qhi + ab);
  short8 ah1 = *(const short8*)(qhi + ab + 512);
  short8 al0 = *(const short8*)(qlo + ab);
  short8 al1 = *(const short8*)(qlo + ab + 512);

  unsigned tv[4][8];
#pragma unroll
  for (int r = 0; r < 4; r++)
#pragma unroll
    for (int k = 0; k < 8; k++) tv[r][k] = 0u;

  for (int kt = 0; kt < 64; kt++) {
    size_t bo = (size_t)(bt0 + kt) * 1024 + lane * 8;
    short8 bh0 = *(const short8*)(BH + bo);
    short8 bh1 = *(const short8*)(BH + bo + 512);
    short8 bl0 = *(const short8*)(BL + bo);
    short8 bl1 = *(const short8*)(BL + bo + 512);
    int key = (ckb + kt) * 16 + col;
    float iv = inv[key];
    bool ok = mask ? (mask[key] >= 0.5f) : true;
    f32x4 c0 = {0.f, 0.f, 0.f, 0.f}, c1 = {0.f, 0.f, 0.f, 0.f};
    c0 = __builtin_amdgcn_mfma_f32_16x16x32_bf16(ah0, bh0, c0, 0, 0, 0);
    c1 = __builtin_amdgcn_mfma_f32_16x16x32_bf16(ah1, bh1, c1, 0, 0, 0);
    c0 = __builtin_amdgcn_mfma_f32_16x16x32_bf16(ah0, bl0, c0, 0, 0, 0);
    c1 = __builtin_amdgcn_mfma_f32_16x16x32_bf16(ah1, bl1, c1, 0, 0, 0);
    c0 = __builtin_amdgcn_mfma_f32_16x16x32_bf16(al0, bh0, c0, 0, 0, 0);
    c1 = __builtin_amdgcn_mfma_f32_16x16x32_bf16(al1, bh1, c1, 0, 0, 0);
#pragma unroll
    for (int r = 0; r < 4; r++) {
      float s = (c0[r] + c1[r]) * iv;
      unsigned pk = (fsort(s) & 0xFFFFF000u) | (unsigned)key;
      pk = ok ? pk : 0u;
      if (pk > tv[r][0]) ins8u(tv[r], pk);
    }
  }

  // butterfly across the 16 cols (lane bits 0..3); partner sets are disjoint
#pragma unroll
  for (int m = 1; m <= 8; m <<= 1) {
#pragma unroll
    for (int r = 0; r < 4; r++) {
      unsigned ov[8];
#pragma unroll
      for (int k = 0; k < 8; k++) ov[k] = (unsigned)__shfl_xor((int)tv[r][k], m, 64);
#pragma unroll
      for (int k = 7; k >= 0; k--)
        if (ov[k] > tv[r][0]) ins8u(tv[r], ov[k]);
    }
  }

  if (col == 0) {
#pragma unroll
    for (int r = 0; r < 4; r++) {
      int q = qt_g * 16 + quad * 4 + r;
#pragma unroll
      for (int k = 0; k < 8; k++)
        PC[(size_t)(row0 + k) * NQ + q] = tv[r][k];
    }
  }
}

__device__ __forceinline__ float dot64(const float4* __restrict__ a,
                                       const float4* __restrict__ b) {
  float a0 = 0.f, a1 = 0.f, a2 = 0.f, a3 = 0.f;
#pragma unroll
  for (int c = 0; c < 16; c++) {
    float4 x = a[c], y = b[c];
    a0 = fmaf(x.x, y.x, a0);
    a1 = fmaf(x.y, y.y, a1);
    a2 = fmaf(x.z, y.z, a2);
    a3 = fmaf(x.w, y.w, a3);
  }
  return (a0 + a1) + (a2 + a3);
}

// ===== kernel 3: exact re-rank of 32 KNN1 candidates + flow_init (16 lanes/q) =====
__global__ __launch_bounds__(256) void k_merge_flow(const unsigned* __restrict__ pc,
                                                    const float* __restrict__ vf,
                                                    const float* __restrict__ pf,
                                                    const float* __restrict__ pts,
                                                    const float* __restrict__ vtx,
                                                    const float* __restrict__ inv_pf,
                                                    float* __restrict__ flow_ws,
                                                    float* __restrict__ out) {
  int T = blockIdx.x * 256 + threadIdx.x;
  int q = T >> 4, c = T & 15, batch = q >> 11;
  const float4* qp = (const float4*)(vf + (size_t)q * DD);
  float tv[8];
  int ti[8];
#pragma unroll
  for (int k = 0; k < 8; k++) { tv[k] = -3.0e38f; ti[k] = 0; }
#pragma unroll
  for (int u = 0; u < 2; u++) {  // 32 candidate rows / 16 lanes
    unsigned pk = pc[(size_t)(c * 2 + u) * NQ + q];
    if (pk) {
      int id = (int)(pk & 0xFFFu);
      int prow = batch * NPP + id;
      float s = dot64(qp, (const float4*)(pf + (size_t)prow * DD)) * inv_pf[prow];
      if (s > tv[0]) ins8(tv, ti, s, id);
    }
  }
#pragma unroll
  for (int m = 1; m <= 8; m <<= 1) {
    float ov[8];
    int oi[8];
#pragma unroll
    for (int k = 0; k < 8; k++) {
      ov[k] = __shfl_xor(tv[k], m, 64);
      oi[k] = __shfl_xor(ti[k], m, 64);
    }
#pragma unroll
    for (int k = 7; k >= 0; k--)
      if (ov[k] > tv[0]) ins8(tv, ti, ov[k], oi[k]);
  }
  int id = ti[0];
#pragma unroll
  for (int k = 1; k < 8; k++) id = (c == k) ? ti[k] : id;

  float ax = 0.f, ay = 0.f, az = 0.f, den = 0.f;
  if (c < 8) {
    int prow = batch * NPP + id;
    float w = dot64(qp, (const float4*)(pf + (size_t)prow * DD));
    ax = (pts[prow * 3 + 0] - vtx[q * 3 + 0]) * w;
    ay = (pts[prow * 3 + 1] - vtx[q * 3 + 1]) * w;
    az = (pts[prow * 3 + 2] - vtx[q * 3 + 2]) * w;
    den = w;
  }
#pragma unroll
  for (int m = 1; m <= 8; m <<= 1) {
    ax += __shfl_xor(ax, m, 64);
    ay += __shfl_xor(ay, m, 64);
    az += __shfl_xor(az, m, 64);
    den += __shfl_xor(den, m, 64);
  }
  if (c == 0) {
    float fx = ax / den, fy = ay / den, fz = az / den;
    flow_ws[q * 4 + 0] = fx;
    flow_ws[q * 4 + 1] = fy;
    flow_ws[q * 4 + 2] = fz;
    out[q * 4 + 0] = fx;
    out[q * 4 + 1] = fy;
    out[q * 4 + 2] = fz;
  }
}

// ===== kernel 4: exact re-rank of 16 KNN2 candidates + interpolate invisible =====
__global__ __launch_bounds__(256) void k_merge_final(const unsigned* __restrict__ pc,
                                                     const float* __restrict__ vf,
                                                     const float* __restrict__ vm,
                                                     const float* __restrict__ inv_vf,
                                                     const float* __restrict__ flow_ws,
                                                     float* __restrict__ out) {
  int T = blockIdx.x * 256 + threadIdx.x;
  int q = T >> 4, c = T & 15, batch = q >> 11;
  if (vm[q] >= 0.5f) return;
  const float4* qp = (const float4*)(vf + (size_t)q * DD);
  float tv[8];
  int ti[8];
#pragma unroll
  for (int k = 0; k < 8; k++) { tv[k] = -3.0e38f; ti[k] = 0; }
  {  // 16 candidate rows / 16 lanes
    unsigned pk = pc[(size_t)c * NQ + q];
    if (pk) {
      int id = (int)(pk & 0xFFFu);
      int krow = batch * NVV + id;
      float s = dot64(qp, (const float4*)(vf + (size_t)krow * DD)) * inv_vf[krow];
      if (s > tv[0]) ins8(tv, ti, s, id);
    }
  }
#pragma unroll
  for (int m = 1; m <= 8; m <<= 1) {
    float ov[8];
    int oi[8];
#pragma unroll
    for (int k = 0; k < 8; k++) {
      ov[k] = __shfl_xor(tv[k], m, 64);
      oi[k] = __shfl_xor(ti[k], m, 64);
    }
#pragma unroll
    for (int k = 7; k >= 0; k--)
      if (ov[k] > tv[0]) ins8(tv, ti, ov[k], oi[k]);
  }
  int id = ti[0];
#pragma unroll
  for (int k = 1; k < 8; k++) id = (c == k) ? ti[k] : id;

  float ax = 0.f, ay = 0.f, az = 0.f, den = 0.f;
  if (c < 8) {
    int krow = batch * NVV + id;
    float w = dot64(qp, (const float4*)(vf + (size_t)krow * DD));
    ax = flow_ws[krow * 4 + 0] * w;
    ay = flow_ws[krow * 4 + 1] * w;
    az = flow_ws[krow * 4 + 2] * w;
    den = w;
  }
#pragma unroll
  for (int m = 1; m <= 8; m <<= 1) {
    ax += __shfl_xor(ax, m, 64);
    ay += __shfl_xor(ay, m, 64);
    az += __shfl_xor(az, m, 64);
    den += __shfl_xor(den, m, 64);
  }
  if (c == 0) {
    out[q * 4 + 0] = ax / den;
    out[q * 4 + 1] = ay / den;
    out[q * 4 + 2] = az / den;
  }
}

extern "C" void kernel_launch(void* const* d_in, const int* in_sizes, int n_in,
                              void* d_out, int out_size, void* d_ws, size_t ws_size,
                              hipStream_t stream) {
  const float* vtx = (const float*)d_in[0];
  const float* pts = (const float*)d_in[1];
  const float* vf = (const float*)d_in[2];
  const float* pf = (const float*)d_in[3];
  const float* lg = (const float*)d_in[4];
  float* out = (float*)d_out;
  float* ws = (float*)d_ws;

  float* vm = ws;
  float* inv_vf = ws + 16384;
  float* inv_pf = ws + 32768;
  float* flow = ws + 65536;
  unsigned* pc1 = (unsigned*)(ws + 131072);
  unsigned* pc2 = (unsigned*)(ws + 655360);
  unsigned short* qhi = (unsigned short*)(ws + 917504);
  unsigned short* qlo = (unsigned short*)(ws + 1441792);
  unsigned short* khi = (unsigned short*)(ws + 1966080);
  unsigned short* klo = (unsigned short*)(ws + 3014656);

  k_prep<<<BB + 3072 + 1536, 256, 0, stream>>>(lg, vf, pf, vm, inv_vf, inv_pf,
                                               qhi, qlo, khi, klo, out);
  k_knn<<<(QT * NC1 + QT * NC2) / 4, 256, 0, stream>>>(qhi, qlo, khi, klo,
                                                       inv_vf, inv_pf, vm, pc1, pc2);
  k_merge_flow<<<NQ * 16 / 256, 256, 0, stream>>>(pc1, vf, pf, pts, vtx,
                                                  inv_pf, flow, out);
  k_merge_final<<<NQ * 16 / 256, 256, 0, stream>>>(pc2, vf, vm, inv_vf, flow, out);
}

// Round 11
// 192.992 us; speedup vs baseline: 3.7164x; 1.3487x over previous
//
#include <hip/hip_runtime.h>
#include <math.h>

#define BB 8
#define NVV 2048
#define NPP 4096
#define DD 64
#define NQ (BB * NVV)     // 16384 vertex rows
#define QT (NQ / 16)      // 1024 query tiles
#define NC1 2             // key chunks KNN1 (128 tiles each)
#define NC2 2             // key chunks KNN2 (64 tiles each)

typedef __attribute__((ext_vector_type(8))) short short8;
typedef __attribute__((ext_vector_type(8))) unsigned short ushort8;
typedef __attribute__((ext_vector_type(4))) float f32x4;

// ws layout (float offsets) -- R10 BUG WAS HERE: qlo was at qhi+262144 but
// qhi holds QT*1024 ushorts = 524288 floats, so qlo clobbered qhi's top half
// (batches 4-7 queries). Corrected strides:
// vm 0 | inv_vf 16384 | inv_pf 32768 | flow 65536
// pc1 @131072 [16][NQ] uint | pc2 @393216 [16][NQ] uint
// qhi @655360 (+524288) | qlo @1179648 (+524288)
// khi @1703936 (+1048576) | klo @2752512 (+1048576) | end 3801088 (~14.5 MB)

__device__ __forceinline__ unsigned short bf16rn(float x) {
  unsigned u = __float_as_uint(x);
  return (unsigned short)((u + 0x7FFFu + ((u >> 16) & 1u)) >> 16);
}
__device__ __forceinline__ float bf2f(unsigned short h) {
  return __uint_as_float(((unsigned)h) << 16);
}

// Branchless sorted-ascending top-8 insert: 7x v_med3_u32 + 1x max.
// No-op when v <= a[0]; no guard, no exec-mask churn. In-place ascending is
// safe: step k reads original a[k],a[k+1], writes a[k] exactly once.
__device__ __forceinline__ void net8(unsigned* a, unsigned v) {
#pragma unroll
  for (int k = 0; k < 7; k++) {
    unsigned r;
    asm("v_med3_u32 %0, %1, %2, %3" : "=v"(r) : "v"(v), "v"(a[k]), "v"(a[k + 1]));
    a[k] = r;
  }
  a[7] = a[7] > v ? a[7] : v;
}

__device__ __forceinline__ void ins8(float* tv, int* ti, float v, int id) {
  bool c1 = v > tv[1], c2 = v > tv[2], c3 = v > tv[3];
  bool c4 = v > tv[4], c5 = v > tv[5], c6 = v > tv[6], c7 = v > tv[7];
  tv[0] = c1 ? tv[1] : v;                ti[0] = c1 ? ti[1] : id;
  tv[1] = c2 ? tv[2] : (c1 ? v : tv[1]); ti[1] = c2 ? ti[2] : (c1 ? id : ti[1]);
  tv[2] = c3 ? tv[3] : (c2 ? v : tv[2]); ti[2] = c3 ? ti[3] : (c2 ? id : ti[2]);
  tv[3] = c4 ? tv[4] : (c3 ? v : tv[3]); ti[3] = c4 ? ti[4] : (c3 ? id : ti[3]);
  tv[4] = c5 ? tv[5] : (c4 ? v : tv[4]); ti[4] = c5 ? ti[5] : (c4 ? id : ti[4]);
  tv[5] = c6 ? tv[6] : (c5 ? v : tv[5]); ti[5] = c6 ? ti[6] : (c5 ? id : ti[5]);
  tv[6] = c7 ? tv[7] : (c6 ? v : tv[6]); ti[6] = c7 ? ti[7] : (c6 ? id : ti[6]);
  tv[7] = c7 ? v : tv[7];                ti[7] = c7 ? id : ti[7];
}

// ===== kernel 1: vm (blocks 0..7) + inv-norms (next 3072) + bf16 frag staging =====
__global__ __launch_bounds__(256) void k_prep(const float* __restrict__ logits,
                                              const float* __restrict__ vf,
                                              const float* __restrict__ pf,
                                              float* __restrict__ vm,
                                              float* __restrict__ inv_vf,
                                              float* __restrict__ inv_pf,
                                              unsigned short* __restrict__ qhi,
                                              unsigned short* __restrict__ qlo,
                                              unsigned short* __restrict__ khi,
                                              unsigned short* __restrict__ klo,
                                              float* __restrict__ out) {
  int bid = blockIdx.x, t = threadIdx.x;
  if (bid < BB) {
    int b = bid;
    __shared__ float smn[4], smx[4];
    float vals[8];
    float mn = 1e30f, mx = -1e30f;
#pragma unroll
    for (int i = 0; i < 8; i++) {
      float x = logits[b * NVV + t + i * 256];
      float s = 1.0f / (1.0f + expf(-x));
      vals[i] = s;
      mn = fminf(mn, s);
      mx = fmaxf(mx, s);
    }
    for (int o = 32; o; o >>= 1) {
      mn = fminf(mn, __shfl_xor(mn, o, 64));
      mx = fmaxf(mx, __shfl_xor(mx, o, 64));
    }
    int w = t >> 6;
    if ((t & 63) == 0) { smn[w] = mn; smx[w] = mx; }
    __syncthreads();
    mn = fminf(fminf(smn[0], smn[1]), fminf(smn[2], smn[3]));
    mx = fmaxf(fmaxf(smx[0], smx[1]), fmaxf(smx[2], smx[3]));
    float range = mx - mn;
#pragma unroll
    for (int i = 0; i < 8; i++) {
      float v = (vals[i] - mn) / range;
      int g = b * NVV + t + i * 256;
      vm[g] = v;
      out[g * 4 + 3] = v;
    }
  } else if (bid < BB + 3072) {
    int T = (bid - BB) * 256 + t;
    int row = T >> 4, c = T & 15;
    const float* src;
    float* dst;
    int r;
    if (row < NQ) { src = vf; dst = inv_vf; r = row; }
    else { src = pf; dst = inv_pf; r = row - NQ; }
    float4 v = *(const float4*)(src + (size_t)r * DD + c * 4);
    float s = v.x * v.x + v.y * v.y + v.z * v.z + v.w * v.w;
#pragma unroll
    for (int m = 1; m <= 8; m <<= 1) s += __shfl_xor(s, m, 64);
    if (c == 0) dst[r] = 1.0f / fmaxf(sqrtf(s), 1e-12f);
  } else {
    // staging: one thread = one (tile,kk,lane) slot of 8 elems; hi/lo bf16 split
    int T = (bid - BB - 3072) * 256 + t;  // 0..393215
    const float* src;
    unsigned short *dh, *dl;
    int s;
    if (T < QT * 128) { s = T; src = vf; dh = qhi; dl = qlo; }
    else { s = T - QT * 128; src = pf; dh = khi; dl = klo; }
    int lane = s & 63, kk = (s >> 6) & 1, tile = s >> 7;
    size_t off = (size_t)(tile * 16 + (lane & 15)) * DD + kk * 32 + ((lane >> 4) & 3) * 8;
    float4 a = *(const float4*)(src + off);
    float4 b = *(const float4*)(src + off + 4);
    float xs[8] = {a.x, a.y, a.z, a.w, b.x, b.y, b.z, b.w};
    ushort8 h, l;
#pragma unroll
    for (int j = 0; j < 8; j++) {
      unsigned short hj = bf16rn(xs[j]);
      h[j] = hj;
      l[j] = bf16rn(xs[j] - bf2f(hj));
    }
    *(ushort8*)(dh + (size_t)s * 8) = h;
    *(ushort8*)(dl + (size_t)s * 8) = l;
  }
}

// ===== kernel 2: MFMA KNN candidate generation (fused KNN1 + KNN2) =====
// Wave = 16 queries (one A tile) x ntiles key tiles, 6 MFMAs/tile (hi/lo bf16
// split). Selection on packed fixed-point uints:
// pk = ((uint)(s*16384+262144) << 12) | key  (|s| <= |q| ~ 12 < 16 headroom by
// Cauchy-Schwarz; 6e-5 quantization -- candidate superset only, merges re-rank
// in exact fp32). KNN2 mask is an EXPLICIT per-key select (R9 lesson: folding
// the mask into inv as -1e30 overflows the uint cvt for negative dots).
// Insert = branchless med3 network (R8 lesson: guarded chains = exec churn).
__global__ __launch_bounds__(256)
void k_knn(const unsigned short* __restrict__ qhi, const unsigned short* __restrict__ qlo,
           const unsigned short* __restrict__ khi, const unsigned short* __restrict__ klo,
           const float* __restrict__ inv_vf, const float* __restrict__ inv_pf,
           const float* __restrict__ vm,
           unsigned* __restrict__ pc1, unsigned* __restrict__ pc2) {
  int wid = (blockIdx.x * 256 + threadIdx.x) >> 6;
  int lane = threadIdx.x & 63, col = lane & 15, quad = lane >> 4;

  const unsigned short *BH, *BL;
  const float *inv, *mask;
  unsigned* PC;
  int qt_g, bt0, row0, ckb, ntiles;
  if (wid < QT * NC1) {  // KNN1: keys = pf
    int ck = wid & (NC1 - 1);
    qt_g = wid / NC1;
    int batch = qt_g >> 7;
    BH = khi; BL = klo;
    inv = inv_pf + batch * NPP;
    mask = nullptr;
    ntiles = 256 / NC1;
    bt0 = batch * 256 + ck * ntiles;
    PC = pc1;
    row0 = ck * 8; ckb = ck * ntiles;
  } else {               // KNN2: keys = vf, visible only
    int w = wid - QT * NC1;
    int ck = w & (NC2 - 1);
    qt_g = w / NC2;
    int batch = qt_g >> 7;
    BH = qhi; BL = qlo;
    inv = inv_vf + batch * NVV;
    mask = vm + batch * NVV;
    ntiles = 128 / NC2;
    bt0 = batch * 128 + ck * ntiles;
    PC = pc2;
    row0 = ck * 8; ckb = ck * ntiles;
  }

  size_t ab = (size_t)qt_g * 1024 + lane * 8;
  short8 ah0 = *(const short8*)(qhi + ab);
  short8 ah1 = *(const short8*)(qhi + ab + 512);
  short8 al0 = *(const short8*)(qlo + ab);
  short8 al1 = *(const short8*)(qlo + ab + 512);

  unsigned tv[4][8];
#pragma unroll
  for (int r = 0; r < 4; r++)
#pragma unroll
    for (int k = 0; k < 8; k++) tv[r][k] = 0u;

#pragma unroll 2
  for (int kt = 0; kt < ntiles; kt++) {
    size_t bo = (size_t)(bt0 + kt) * 1024 + lane * 8;
    short8 bh0 = *(const short8*)(BH + bo);
    short8 bh1 = *(const short8*)(BH + bo + 512);
    short8 bl0 = *(const short8*)(BL + bo);
    short8 bl1 = *(const short8*)(BL + bo + 512);
    int key = (ckb + kt) * 16 + col;
    float iv = inv[key];
    bool ok = mask ? (mask[key] >= 0.5f) : true;
    f32x4 c0 = {0.f, 0.f, 0.f, 0.f}, c1 = {0.f, 0.f, 0.f, 0.f};
    c0 = __builtin_amdgcn_mfma_f32_16x16x32_bf16(ah0, bh0, c0, 0, 0, 0);
    c1 = __builtin_amdgcn_mfma_f32_16x16x32_bf16(ah1, bh1, c1, 0, 0, 0);
    c0 = __builtin_amdgcn_mfma_f32_16x16x32_bf16(ah0, bl0, c0, 0, 0, 0);
    c1 = __builtin_amdgcn_mfma_f32_16x16x32_bf16(ah1, bl1, c1, 0, 0, 0);
    c0 = __builtin_amdgcn_mfma_f32_16x16x32_bf16(al0, bh0, c0, 0, 0, 0);
    c1 = __builtin_amdgcn_mfma_f32_16x16x32_bf16(al1, bh1, c1, 0, 0, 0);
#pragma unroll
    for (int r = 0; r < 4; r++) {
      float s = (c0[r] + c1[r]) * iv;
      unsigned u = (unsigned)fmaxf(fmaf(s, 16384.0f, 262144.0f), 0.0f);
      unsigned pk = (u << 12) | (unsigned)key;
      pk = ok ? pk : 0u;
      net8(tv[r], pk);
    }
  }

  // butterfly across the 16 cols (lane bits 0..3)
#pragma unroll
  for (int m = 1; m <= 8; m <<= 1) {
#pragma unroll
    for (int r = 0; r < 4; r++) {
      unsigned ov[8];
#pragma unroll
      for (int k = 0; k < 8; k++) ov[k] = (unsigned)__shfl_xor((int)tv[r][k], m, 64);
#pragma unroll
      for (int k = 7; k >= 0; k--) net8(tv[r], ov[k]);
    }
  }

  if (col == 0) {
#pragma unroll
    for (int r = 0; r < 4; r++) {
      int q = qt_g * 16 + quad * 4 + r;
#pragma unroll
      for (int k = 0; k < 8; k++)
        PC[(size_t)(row0 + k) * NQ + q] = tv[r][k];
    }
  }
}

__device__ __forceinline__ float dot64(const float4* __restrict__ a,
                                       const float4* __restrict__ b) {
  float a0 = 0.f, a1 = 0.f, a2 = 0.f, a3 = 0.f;
#pragma unroll
  for (int c = 0; c < 16; c++) {
    float4 x = a[c], y = b[c];
    a0 = fmaf(x.x, y.x, a0);
    a1 = fmaf(x.y, y.y, a1);
    a2 = fmaf(x.z, y.z, a2);
    a3 = fmaf(x.w, y.w, a3);
  }
  return (a0 + a1) + (a2 + a3);
}

// ===== kernel 3: exact re-rank of 16 KNN1 candidates + flow_init (16 lanes/q) =====
__global__ __launch_bounds__(256) void k_merge_flow(const unsigned* __restrict__ pc,
                                                    const float* __restrict__ vf,
                                                    const float* __restrict__ pf,
                                                    const float* __restrict__ pts,
                                                    const float* __restrict__ vtx,
                                                    const float* __restrict__ inv_pf,
                                                    float* __restrict__ flow_ws,
                                                    float* __restrict__ out) {
  int T = blockIdx.x * 256 + threadIdx.x;
  int q = T >> 4, c = T & 15, batch = q >> 11;
  const float4* qp = (const float4*)(vf + (size_t)q * DD);
  float tv[8];
  int ti[8];
#pragma unroll
  for (int k = 0; k < 8; k++) { tv[k] = -3.0e38f; ti[k] = 0; }
  {  // 16 candidate rows / 16 lanes
    unsigned pk = pc[(size_t)c * NQ + q];
    int id = (int)(pk & 0xFFFu);
    int prow = batch * NPP + id;
    float s = dot64(qp, (const float4*)(pf + (size_t)prow * DD)) * inv_pf[prow];
    ins8(tv, ti, s, id);
  }
#pragma unroll
  for (int m = 1; m <= 8; m <<= 1) {
    float ov[8];
    int oi[8];
#pragma unroll
    for (int k = 0; k < 8; k++) {
      ov[k] = __shfl_xor(tv[k], m, 64);
      oi[k] = __shfl_xor(ti[k], m, 64);
    }
#pragma unroll
    for (int k = 7; k >= 0; k--)
      if (ov[k] > tv[0]) ins8(tv, ti, ov[k], oi[k]);
  }
  int id = ti[0];
#pragma unroll
  for (int k = 1; k < 8; k++) id = (c == k) ? ti[k] : id;

  float ax = 0.f, ay = 0.f, az = 0.f, den = 0.f;
  if (c < 8) {
    int prow = batch * NPP + id;
    float w = dot64(qp, (const float4*)(pf + (size_t)prow * DD));
    ax = (pts[prow * 3 + 0] - vtx[q * 3 + 0]) * w;
    ay = (pts[prow * 3 + 1] - vtx[q * 3 + 1]) * w;
    az = (pts[prow * 3 + 2] - vtx[q * 3 + 2]) * w;
    den = w;
  }
#pragma unroll
  for (int m = 1; m <= 8; m <<= 1) {
    ax += __shfl_xor(ax, m, 64);
    ay += __shfl_xor(ay, m, 64);
    az += __shfl_xor(az, m, 64);
    den += __shfl_xor(den, m, 64);
  }
  if (c == 0) {
    float fx = ax / den, fy = ay / den, fz = az / den;
    flow_ws[q * 4 + 0] = fx;
    flow_ws[q * 4 + 1] = fy;
    flow_ws[q * 4 + 2] = fz;
    out[q * 4 + 0] = fx;
    out[q * 4 + 1] = fy;
    out[q * 4 + 2] = fz;
  }
}

// ===== kernel 4: exact re-rank of 16 KNN2 candidates + interpolate invisible =====
__global__ __launch_bounds__(256) void k_merge_final(const unsigned* __restrict__ pc,
                                                     const float* __restrict__ vf,
                                                     const float* __restrict__ vm,
                                                     const float* __restrict__ inv_vf,
                                                     const float* __restrict__ flow_ws,
                                                     float* __restrict__ out) {
  int T = blockIdx.x * 256 + threadIdx.x;
  int q = T >> 4, c = T & 15, batch = q >> 11;
  if (vm[q] >= 0.5f) return;
  const float4* qp = (const float4*)(vf + (size_t)q * DD);
  float tv[8];
  int ti[8];
#pragma unroll
  for (int k = 0; k < 8; k++) { tv[k] = -3.0e38f; ti[k] = 0; }
  {  // 16 candidate rows / 16 lanes; pk <= 0xFFF = masked sentinel, skip
    unsigned pk = pc[(size_t)c * NQ + q];
    if (pk > 0xFFFu) {
      int id = (int)(pk & 0xFFFu);
      int krow = batch * NVV + id;
      float s = dot64(qp, (const float4*)(vf + (size_t)krow * DD)) * inv_vf[krow];
      ins8(tv, ti, s, id);
    }
  }
#pragma unroll
  for (int m = 1; m <= 8; m <<= 1) {
    float ov[8];
    int oi[8];
#pragma unroll
    for (int k = 0; k < 8; k++) {
      ov[k] = __shfl_xor(tv[k], m, 64);
      oi[k] = __shfl_xor(ti[k], m, 64);
    }
#pragma unroll
    for (int k = 7; k >= 0; k--)
      if (ov[k] > tv[0]) ins8(tv, ti, ov[k], oi[k]);
  }
  int id = ti[0];
#pragma unroll
  for (int k = 1; k < 8; k++) id = (c == k) ? ti[k] : id;

  float ax = 0.f, ay = 0.f, az = 0.f, den = 0.f;
  if (c < 8) {
    int krow = batch * NVV + id;
    float w = dot64(qp, (const float4*)(vf + (size_t)krow * DD));
    ax = flow_ws[krow * 4 + 0] * w;
    ay = flow_ws[krow * 4 + 1] * w;
    az = flow_ws[krow * 4 + 2] * w;
    den = w;
  }
#pragma unroll
  for (int m = 1; m <= 8; m <<= 1) {
    ax += __shfl_xor(ax, m, 64);
    ay += __shfl_xor(ay, m, 64);
    az += __shfl_xor(az, m, 64);
    den += __shfl_xor(den, m, 64);
  }
  if (c == 0) {
    out[q * 4 + 0] = ax / den;
    out[q * 4 + 1] = ay / den;
    out[q * 4 + 2] = az / den;
  }
}

extern "C" void kernel_launch(void* const* d_in, const int* in_sizes, int n_in,
                              void* d_out, int out_size, void* d_ws, size_t ws_size,
                              hipStream_t stream) {
  const float* vtx = (const float*)d_in[0];
  const float* pts = (const float*)d_in[1];
  const float* vf = (const float*)d_in[2];
  const float* pf = (const float*)d_in[3];
  const float* lg = (const float*)d_in[4];
  float* out = (float*)d_out;
  float* ws = (float*)d_ws;

  float* vm = ws;
  float* inv_vf = ws + 16384;
  float* inv_pf = ws + 32768;
  float* flow = ws + 65536;
  unsigned* pc1 = (unsigned*)(ws + 131072);
  unsigned* pc2 = (unsigned*)(ws + 393216);
  unsigned short* qhi = (unsigned short*)(ws + 655360);
  unsigned short* qlo = (unsigned short*)(ws + 1179648);   // qhi + 524288 floats
  unsigned short* khi = (unsigned short*)(ws + 1703936);   // qlo + 524288
  unsigned short* klo = (unsigned short*)(ws + 2752512);   // khi + 1048576

  k_prep<<<BB + 3072 + 1536, 256, 0, stream>>>(lg, vf, pf, vm, inv_vf, inv_pf,
                                               qhi, qlo, khi, klo, out);
  k_knn<<<(QT * NC1 + QT * NC2) / 4, 256, 0, stream>>>(qhi, qlo, khi, klo,
                                                       inv_vf, inv_pf, vm, pc1, pc2);
  k_merge_flow<<<NQ * 16 / 256, 256, 0, stream>>>(pc1, vf, pf, pts, vtx,
                                                  inv_pf, flow, out);
  k_merge_final<<<NQ * 16 / 256, 256, 0, stream>>>(pc2, vf, vm, inv_vf, flow, out);
}